// Round 3
// baseline (175.597 us; speedup 1.0000x reference)
//
#include <hip/hip_runtime.h>

typedef unsigned short u16;
typedef float f32x4 __attribute__((ext_vector_type(4)));
typedef __bf16 bf16x4 __attribute__((ext_vector_type(4)));
typedef __bf16 bf16x8 __attribute__((ext_vector_type(8)));

#define B_ 8
#define N_ 4096
#define C_ 256
#define NKV 256

__device__ inline u16 f2bf(float f) {
    union { float f; unsigned u; } v; v.f = f;
    unsigned r = v.u + 0x7FFF + ((v.u >> 16) & 1);
    return (u16)(r >> 16);
}

// ---------------- prep: weights -> bf16 (torch [out,in] layout kept as Bt[N][K]) ----------------
__global__ __launch_bounds__(256) void prep_w(
    const float* __restrict__ qw, const float* __restrict__ kvw,
    const float* __restrict__ pw, const float* __restrict__ srw,
    u16* __restrict__ wq, u16* __restrict__ wkv, u16* __restrict__ wp, u16* __restrict__ wsr)
{
    int t = blockIdx.x * 256 + threadIdx.x;
    int stride = gridDim.x * 256;
    for (int i = t; i < 65536; i += stride) { wq[i] = f2bf(qw[i]); wp[i] = f2bf(pw[i]); }
    for (int i = t; i < 131072; i += stride) wkv[i] = f2bf(kvw[i]);
    // wsr[o][(kh*4+kw)*256 + ci] = srw[o][ci][kh][kw]
    for (int i = t; i < 1048576; i += stride) {
        int o = i >> 12, k = i & 4095;
        int ci = k & 255, khkw = k >> 8;
        wsr[i] = f2bf(srw[(size_t)(o * 256 + ci) * 16 + khkw]);
    }
}

// ---------------- prep: x -> bf16 [B*N][C]  and  im2col patches [B*256][4096] ----------------
__global__ __launch_bounds__(256) void prep_x(
    const float* __restrict__ x, u16* __restrict__ xb, u16* __restrict__ patches)
{
    size_t base = ((size_t)blockIdx.x * 256 + threadIdx.x) * 4;
    float4 v = *(const float4*)(x + base);
    ushort4 o;
    o.x = f2bf(v.x); o.y = f2bf(v.y); o.z = f2bf(v.z); o.w = f2bf(v.w);
    *(ushort4*)(xb + base) = o;
    int c = (int)(base & 255);
    int n = (int)((base >> 8) & 4095);
    int b = (int)(base >> 20);
    int hh = n >> 6, ww = n & 63;
    int p = (hh >> 2) * 16 + (ww >> 2);
    int k = ((hh & 3) * 4 + (ww & 3)) * 256 + c;
    *(ushort4*)(patches + (size_t)(b * 256 + p) * 4096 + k) = o;
}

// ---------------- generic 128x128 bf16 MFMA GEMM:  out = A[M,K] @ Bt[N,K]^T (+bias) ----------------
// OUTMODE: 0 = f32 out + bias, 1 = bf16 out + bias, 2 = f32 split-K partial (offset z*M*N, no bias)
template<int OUTMODE>
__global__ __launch_bounds__(256, 2) void gemm128(
    const u16* __restrict__ A, const u16* __restrict__ Bt,
    const float* __restrict__ bias, void* __restrict__ outp,
    int M, int Nn, int K, int kchunk)
{
    __shared__ __align__(16) u16 As[128 * 40];
    __shared__ __align__(16) u16 Bs[128 * 40];
    const int tid = threadIdx.x;
    const int bm = blockIdx.x, bn = blockIdx.y, bz = blockIdx.z;
    const int k0 = bz * kchunk;
    const int wid = tid >> 6, lane = tid & 63;
    const int wr = wid >> 1, wc = wid & 1;
    const int lrow = lane & 15, lkg = lane >> 4;

    f32x4 acc[4][4] = {};

    const int rS = tid >> 2, cS = (tid & 3) * 8;
    const u16* aSrc = A  + (size_t)(bm * 128 + rS) * K + k0 + cS;
    const u16* bSrc = Bt + (size_t)(bn * 128 + rS) * K + k0 + cS;
    u16* aDst = As + rS * 40 + cS;
    u16* bDst = Bs + rS * 40 + cS;

    for (int kk = 0; kk < kchunk; kk += 32) {
        *(int4*)aDst             = *(const int4*)(aSrc + kk);
        *(int4*)(aDst + 64 * 40) = *(const int4*)(aSrc + (size_t)64 * K + kk);
        *(int4*)bDst             = *(const int4*)(bSrc + kk);
        *(int4*)(bDst + 64 * 40) = *(const int4*)(bSrc + (size_t)64 * K + kk);
        __syncthreads();
        bf16x8 af[4], bff[4];
#pragma unroll
        for (int i = 0; i < 4; ++i) {
            af[i]  = *(const bf16x8*)(As + (wr * 64 + i * 16 + lrow) * 40 + lkg * 8);
            bff[i] = *(const bf16x8*)(Bs + (wc * 64 + i * 16 + lrow) * 40 + lkg * 8);
        }
#pragma unroll
        for (int i = 0; i < 4; ++i)
#pragma unroll
            for (int j = 0; j < 4; ++j)
                acc[i][j] = __builtin_amdgcn_mfma_f32_16x16x32_bf16(af[i], bff[j], acc[i][j], 0, 0, 0);
        __syncthreads();
    }

    const int row0 = bm * 128 + wr * 64;
    const int col0 = bn * 128 + wc * 64;
    if constexpr (OUTMODE == 2) {
        float* o = (float*)outp + (size_t)bz * M * Nn;
#pragma unroll
        for (int i = 0; i < 4; ++i)
#pragma unroll
            for (int j = 0; j < 4; ++j)
#pragma unroll
                for (int reg = 0; reg < 4; ++reg)
                    o[(size_t)(row0 + i * 16 + lkg * 4 + reg) * Nn + col0 + j * 16 + lrow] = acc[i][j][reg];
    } else {
#pragma unroll
        for (int j = 0; j < 4; ++j) {
            const int col = col0 + j * 16 + lrow;
            const float bv = bias[col];
#pragma unroll
            for (int i = 0; i < 4; ++i)
#pragma unroll
                for (int reg = 0; reg < 4; ++reg) {
                    const size_t idx = (size_t)(row0 + i * 16 + lkg * 4 + reg) * Nn + col;
                    const float val = acc[i][j][reg] + bv;
                    if constexpr (OUTMODE == 1) ((u16*)outp)[idx] = f2bf(val);
                    else                        ((float*)outp)[idx] = val;
                }
        }
    }
}

// ---------------- LN over conv partial sums: xsr = LN(sum_z part + sr_b) -> bf16 ----------------
__global__ __launch_bounds__(256) void ln_kernel(
    const float* __restrict__ part, const float* __restrict__ srb,
    const float* __restrict__ g, const float* __restrict__ bb, u16* __restrict__ out)
{
    const int row = blockIdx.x, c = threadIdx.x;
    const size_t idx = (size_t)row * 256 + c;
    float v = srb[c] + part[idx] + part[idx + 524288] + part[idx + 2 * 524288] + part[idx + 3 * 524288];
    float s = v;
#pragma unroll
    for (int m = 1; m < 64; m <<= 1) s += __shfl_xor(s, m);
    __shared__ float red[4];
    if ((c & 63) == 0) red[c >> 6] = s;
    __syncthreads();
    float tot = red[0] + red[1] + red[2] + red[3];
    float mu = tot * (1.0f / 256.0f);
    float d = v - mu;
    float s2 = d * d;
#pragma unroll
    for (int m = 1; m < 64; m <<= 1) s2 += __shfl_xor(s2, m);
    __syncthreads();
    if ((c & 63) == 0) red[c >> 6] = s2;
    __syncthreads();
    float var = (red[0] + red[1] + red[2] + red[3]) * (1.0f / 256.0f);
    out[idx] = f2bf(d * rsqrtf(var + 1e-5f) * g[c] + bb[c]);
}

// ---------------- fused attention v3: swapped QK^T, P in registers, 16x16x32 PV ----------------
// Per block: (b, h, 256 query rows). Stage K[256][40] + V^T[32][264] once, then 4 x 64-row tiles.
// Per wave per tile: 16 q-rows. S^T = mfma(K_frag, Q_frag) -> lane holds S[q=lrow][k=nf*16+lkg*4+reg].
// PV uses 16x16x32 with the shared k-bijection slot(lkg,e) = 32*nf2 + (e<4 ? lkg*4+e : 16+lkg*4+e-4):
// A-frag = concat(pa[2*nf2], pa[2*nf2+1]) (pure register), B-frag = two ds_read_b64 from Vt.
#define QROWS 256
__global__ __launch_bounds__(256, 4) void attn_kernel(
    const u16* __restrict__ qbuf, const u16* __restrict__ kvbuf, u16* __restrict__ obuf)
{
    __shared__ __align__(16) u16 Ks[256 * 40];   // 20480 B
    __shared__ __align__(16) u16 Vt[32 * 264];   // 16896 B  Vt[d][k]
    const int qt = blockIdx.x, h = blockIdx.y, b = blockIdx.z;
    const int tid = threadIdx.x;
    const int wid = tid >> 6, lane = tid & 63;
    const int lrow = lane & 15, lkg = lane >> 4;

    // stage K: thread t -> k-row t (4 x 16B)
    {
        const u16* ks = kvbuf + (size_t)(b * 256 + tid) * 512 + h * 32;
        u16* kd = Ks + tid * 40;
#pragma unroll
        for (int c = 0; c < 4; ++c)
            *(int4*)(kd + c * 8) = *(const int4*)(ks + c * 8);
    }
    // stage V^T: thread t reads v-row t, scatters 32 u16 (2-way conflicts only)
    {
        const u16* vs = kvbuf + (size_t)(b * 256 + tid) * 512 + 256 + h * 32;
#pragma unroll
        for (int j = 0; j < 8; ++j) {
            ushort4 vv = *(const ushort4*)(vs + j * 4);
            Vt[(j * 4 + 0) * 264 + tid] = vv.x;
            Vt[(j * 4 + 1) * 264 + tid] = vv.y;
            Vt[(j * 4 + 2) * 264 + tid] = vv.z;
            Vt[(j * 4 + 3) * 264 + tid] = vv.w;
        }
    }
    __syncthreads();

    const float cexp = 0.17677669529663687f * 1.4426950408889634f;
    const int qcol = h * 32 + lkg * 8;

    for (int it = 0; it < QROWS / 64; ++it) {
        const int q0 = qt * QROWS + it * 64 + wid * 16;  // q-row base within batch b
        // Q B-fragment straight from global: contiguous 16B per lane
        bf16x8 qf = *(const bf16x8*)(qbuf + (size_t)(b * 4096 + q0 + lrow) * 256 + qcol);

        f32x4 acc[16];
#pragma unroll
        for (int nf = 0; nf < 16; ++nf) acc[nf] = (f32x4){0.f, 0.f, 0.f, 0.f};
#pragma unroll
        for (int nf = 0; nf < 16; ++nf) {
            bf16x8 kf = *(const bf16x8*)(Ks + (nf * 16 + lrow) * 40 + lkg * 8);
            acc[nf] = __builtin_amdgcn_mfma_f32_16x16x32_bf16(kf, qf, acc[nf], 0, 0, 0);
        }

        // softmax over k: 64 values in-lane (q = q0+lrow), then across the 4 lkg groups
        float m0 = -1e30f, m1 = -1e30f, m2 = -1e30f, m3 = -1e30f;
#pragma unroll
        for (int nf = 0; nf < 16; ++nf) {
            m0 = fmaxf(m0, acc[nf][0]); m1 = fmaxf(m1, acc[nf][1]);
            m2 = fmaxf(m2, acc[nf][2]); m3 = fmaxf(m3, acc[nf][3]);
        }
        float m = fmaxf(fmaxf(m0, m1), fmaxf(m2, m3));
        m = fmaxf(m, __shfl_xor(m, 16));
        m = fmaxf(m, __shfl_xor(m, 32));
        float s = 0.f;
#pragma unroll
        for (int nf = 0; nf < 16; ++nf) {
#pragma unroll
            for (int r = 0; r < 4; ++r) {
                float p = exp2f((acc[nf][r] - m) * cexp);
                acc[nf][r] = p; s += p;
            }
        }
        s += __shfl_xor(s, 16);
        s += __shfl_xor(s, 32);
        const float inv = 1.0f / s;

        // P -> bf16 A-fragments (k-chunk nf2 holds k = 32*nf2 + {lkg*4+e | 16+lkg*4+e})
        bf16x8 pa8[8];
#pragma unroll
        for (int nf2 = 0; nf2 < 8; ++nf2) {
            bf16x8 pv;
            pv[0] = (__bf16)acc[2 * nf2][0];     pv[1] = (__bf16)acc[2 * nf2][1];
            pv[2] = (__bf16)acc[2 * nf2][2];     pv[3] = (__bf16)acc[2 * nf2][3];
            pv[4] = (__bf16)acc[2 * nf2 + 1][0]; pv[5] = (__bf16)acc[2 * nf2 + 1][1];
            pv[6] = (__bf16)acc[2 * nf2 + 1][2]; pv[7] = (__bf16)acc[2 * nf2 + 1][3];
            pa8[nf2] = pv;
        }

        // O = P @ V via 16x16x32 with matching B-side bijection (two b64 reads per frag)
        f32x4 o0 = (f32x4){0.f, 0.f, 0.f, 0.f};
        f32x4 o1 = (f32x4){0.f, 0.f, 0.f, 0.f};
#pragma unroll
        for (int nf2 = 0; nf2 < 8; ++nf2) {
            bf16x4 lo0 = *(const bf16x4*)(Vt + lrow * 264 + nf2 * 32 + lkg * 4);
            bf16x4 hi0 = *(const bf16x4*)(Vt + lrow * 264 + nf2 * 32 + 16 + lkg * 4);
            bf16x4 lo1 = *(const bf16x4*)(Vt + (16 + lrow) * 264 + nf2 * 32 + lkg * 4);
            bf16x4 hi1 = *(const bf16x4*)(Vt + (16 + lrow) * 264 + nf2 * 32 + 16 + lkg * 4);
            bf16x8 v0 = __builtin_shufflevector(lo0, hi0, 0, 1, 2, 3, 4, 5, 6, 7);
            bf16x8 v1 = __builtin_shufflevector(lo1, hi1, 0, 1, 2, 3, 4, 5, 6, 7);
            o0 = __builtin_amdgcn_mfma_f32_16x16x32_bf16(pa8[nf2], v0, o0, 0, 0, 0);
            o1 = __builtin_amdgcn_mfma_f32_16x16x32_bf16(pa8[nf2], v1, o1, 0, 0, 0);
        }

        // deferred 1/sum: gather inv for q = q0 + lkg*4 + r from lanes 0..15
        float invq[4];
#pragma unroll
        for (int r = 0; r < 4; ++r) invq[r] = __shfl(inv, lkg * 4 + r);

        const size_t obase = (size_t)(b * 4096 + q0);
#pragma unroll
        for (int r = 0; r < 4; ++r) {
            u16* op = obuf + (obase + lkg * 4 + r) * 256 + h * 32 + lrow;
            op[0]  = f2bf(o0[r] * invq[r]);
            op[16] = f2bf(o1[r] * invq[r]);
        }
    }
}

extern "C" void kernel_launch(void* const* d_in, const int* in_sizes, int n_in,
                              void* d_out, int out_size, void* d_ws, size_t ws_size,
                              hipStream_t stream)
{
    (void)in_sizes; (void)n_in; (void)out_size; (void)ws_size;
    const float* x   = (const float*)d_in[0];
    const float* qw  = (const float*)d_in[3];
    const float* qb  = (const float*)d_in[4];
    const float* kvw = (const float*)d_in[5];
    const float* kvb = (const float*)d_in[6];
    const float* srw = (const float*)d_in[7];
    const float* srb = (const float*)d_in[8];
    const float* lng = (const float*)d_in[9];
    const float* lnb = (const float*)d_in[10];
    const float* pw  = (const float*)d_in[11];
    const float* pb  = (const float*)d_in[12];

    char* ws = (char*)d_ws;
    u16*   xb      = (u16*)(ws + 0);          // 16.78 MB  x as bf16 [32768][256]
    u16*   patches = (u16*)(ws + 16777216);   // 16.78 MB  im2col [2048][4096]; later reused as attn_out
    float* part    = (float*)(ws + 33554432); //  8.39 MB  conv split-K partials [4][2048][256]
    u16*   wsr     = (u16*)(ws + 41943040);   //  2.10 MB
    u16*   wqb     = (u16*)(ws + 44040192);
    u16*   wkvb    = (u16*)(ws + 44171264);
    u16*   wpb     = (u16*)(ws + 44433408);
    u16*   xsr     = (u16*)(ws + 44564480);   //  1.05 MB  LN output bf16 [2048][256]
    u16*   kvo     = (u16*)(ws + 45613056);   //  2.10 MB  kv bf16 [2048][512]
    u16*   qbuf    = (u16*)d_out;             // q bf16 [32768][256] in d_out scratch (overwritten by proj)

    prep_w<<<1024, 256, 0, stream>>>(qw, kvw, pw, srw, wqb, wkvb, wpb, wsr);
    prep_x<<<8192, 256, 0, stream>>>(x, xb, patches);
    // conv as GEMM, split-K x4 -> f32 partials
    gemm128<2><<<dim3(16, 2, 4), 256, 0, stream>>>(patches, wsr, nullptr, part, 2048, 256, 4096, 1024);
    ln_kernel<<<2048, 256, 0, stream>>>(part, srb, lng, lnb, xsr);
    gemm128<1><<<dim3(16, 4, 1), 256, 0, stream>>>(xsr, wkvb, kvb, kvo, 2048, 512, 256, 256);
    gemm128<1><<<dim3(256, 2, 1), 256, 0, stream>>>(xb, wqb, qb, qbuf, 32768, 256, 256, 256);
    attn_kernel<<<dim3(16, 8, 8), 256, 0, stream>>>(qbuf, kvo, patches);
    gemm128<0><<<dim3(256, 2, 1), 256, 0, stream>>>(patches, wpb, pb, d_out, 32768, 256, 256, 256);
}

// Round 4
// 115.434 us; speedup vs baseline: 1.5212x; 1.5212x over previous
//
#include <hip/hip_runtime.h>

typedef unsigned short u16;
typedef float f32x4 __attribute__((ext_vector_type(4)));
typedef __bf16 bf16x4 __attribute__((ext_vector_type(4)));
typedef __bf16 bf16x8 __attribute__((ext_vector_type(8)));

#define B_ 8
#define N_ 4096
#define C_ 256
#define NKV 256

__device__ inline u16 f2bf(float f) {
    union { float f; unsigned u; } v; v.f = f;
    unsigned r = v.u + 0x7FFF + ((v.u >> 16) & 1);
    return (u16)(r >> 16);
}

// ---------------- prep: weights -> bf16 (torch [out,in] layout kept as Bt[N][K]) ----------------
__global__ __launch_bounds__(256) void prep_w(
    const float* __restrict__ qw, const float* __restrict__ kvw,
    const float* __restrict__ pw, const float* __restrict__ srw,
    u16* __restrict__ wq, u16* __restrict__ wkv, u16* __restrict__ wp, u16* __restrict__ wsr)
{
    int t = blockIdx.x * 256 + threadIdx.x;
    int stride = gridDim.x * 256;
    for (int i = t; i < 65536; i += stride) { wq[i] = f2bf(qw[i]); wp[i] = f2bf(pw[i]); }
    for (int i = t; i < 131072; i += stride) wkv[i] = f2bf(kvw[i]);
    // wsr[o][(kh*4+kw)*256 + ci] = srw[o][ci][kh][kw]
    for (int i = t; i < 1048576; i += stride) {
        int o = i >> 12, k = i & 4095;
        int ci = k & 255, khkw = k >> 8;
        wsr[i] = f2bf(srw[(size_t)(o * 256 + ci) * 16 + khkw]);
    }
}

// ---------------- prep: x -> bf16 [B*N][C]  and  im2col patches [B*256][4096] ----------------
__global__ __launch_bounds__(256) void prep_x(
    const float* __restrict__ x, u16* __restrict__ xb, u16* __restrict__ patches)
{
    size_t base = ((size_t)blockIdx.x * 256 + threadIdx.x) * 4;
    float4 v = *(const float4*)(x + base);
    ushort4 o;
    o.x = f2bf(v.x); o.y = f2bf(v.y); o.z = f2bf(v.z); o.w = f2bf(v.w);
    *(ushort4*)(xb + base) = o;
    int c = (int)(base & 255);
    int n = (int)((base >> 8) & 4095);
    int b = (int)(base >> 20);
    int hh = n >> 6, ww = n & 63;
    int p = (hh >> 2) * 16 + (ww >> 2);
    int k = ((hh & 3) * 4 + (ww & 3)) * 256 + c;
    *(ushort4*)(patches + (size_t)(b * 256 + p) * 4096 + k) = o;
}

// ---------------- generic 128x128 bf16 MFMA GEMM:  out = A[M,K] @ Bt[N,K]^T (+bias) ----------------
// OUTMODE: 0 = f32 out + bias, 1 = bf16 out + bias, 2 = f32 split-K partial (offset z*M*N, no bias)
template<int OUTMODE>
__global__ __launch_bounds__(256, 2) void gemm128(
    const u16* __restrict__ A, const u16* __restrict__ Bt,
    const float* __restrict__ bias, void* __restrict__ outp,
    int M, int Nn, int K, int kchunk)
{
    __shared__ __align__(16) u16 As[128 * 40];
    __shared__ __align__(16) u16 Bs[128 * 40];
    const int tid = threadIdx.x;
    const int bm = blockIdx.x, bn = blockIdx.y, bz = blockIdx.z;
    const int k0 = bz * kchunk;
    const int wid = tid >> 6, lane = tid & 63;
    const int wr = wid >> 1, wc = wid & 1;
    const int lrow = lane & 15, lkg = lane >> 4;

    f32x4 acc[4][4] = {};

    const int rS = tid >> 2, cS = (tid & 3) * 8;
    const u16* aSrc = A  + (size_t)(bm * 128 + rS) * K + k0 + cS;
    const u16* bSrc = Bt + (size_t)(bn * 128 + rS) * K + k0 + cS;
    u16* aDst = As + rS * 40 + cS;
    u16* bDst = Bs + rS * 40 + cS;

    for (int kk = 0; kk < kchunk; kk += 32) {
        *(int4*)aDst             = *(const int4*)(aSrc + kk);
        *(int4*)(aDst + 64 * 40) = *(const int4*)(aSrc + (size_t)64 * K + kk);
        *(int4*)bDst             = *(const int4*)(bSrc + kk);
        *(int4*)(bDst + 64 * 40) = *(const int4*)(bSrc + (size_t)64 * K + kk);
        __syncthreads();
        bf16x8 af[4], bff[4];
#pragma unroll
        for (int i = 0; i < 4; ++i) {
            af[i]  = *(const bf16x8*)(As + (wr * 64 + i * 16 + lrow) * 40 + lkg * 8);
            bff[i] = *(const bf16x8*)(Bs + (wc * 64 + i * 16 + lrow) * 40 + lkg * 8);
        }
#pragma unroll
        for (int i = 0; i < 4; ++i)
#pragma unroll
            for (int j = 0; j < 4; ++j)
                acc[i][j] = __builtin_amdgcn_mfma_f32_16x16x32_bf16(af[i], bff[j], acc[i][j], 0, 0, 0);
        __syncthreads();
    }

    const int row0 = bm * 128 + wr * 64;
    const int col0 = bn * 128 + wc * 64;
    if constexpr (OUTMODE == 2) {
        float* o = (float*)outp + (size_t)bz * M * Nn;
#pragma unroll
        for (int i = 0; i < 4; ++i)
#pragma unroll
            for (int j = 0; j < 4; ++j)
#pragma unroll
                for (int reg = 0; reg < 4; ++reg)
                    o[(size_t)(row0 + i * 16 + lkg * 4 + reg) * Nn + col0 + j * 16 + lrow] = acc[i][j][reg];
    } else {
#pragma unroll
        for (int j = 0; j < 4; ++j) {
            const int col = col0 + j * 16 + lrow;
            const float bv = bias[col];
#pragma unroll
            for (int i = 0; i < 4; ++i)
#pragma unroll
                for (int reg = 0; reg < 4; ++reg) {
                    const size_t idx = (size_t)(row0 + i * 16 + lkg * 4 + reg) * Nn + col;
                    const float val = acc[i][j][reg] + bv;
                    if constexpr (OUTMODE == 1) ((u16*)outp)[idx] = f2bf(val);
                    else                        ((float*)outp)[idx] = val;
                }
        }
    }
}

// ---------------- LN over conv partial sums: xsr = LN(sum_z part + sr_b) -> bf16 ----------------
__global__ __launch_bounds__(256) void ln_kernel(
    const float* __restrict__ part, const float* __restrict__ srb,
    const float* __restrict__ g, const float* __restrict__ bb, u16* __restrict__ out)
{
    const int row = blockIdx.x, c = threadIdx.x;
    const size_t idx = (size_t)row * 256 + c;
    float v = srb[c] + part[idx] + part[idx + 524288] + part[idx + 2 * 524288] + part[idx + 3 * 524288];
    float s = v;
#pragma unroll
    for (int m = 1; m < 64; m <<= 1) s += __shfl_xor(s, m);
    __shared__ float red[4];
    if ((c & 63) == 0) red[c >> 6] = s;
    __syncthreads();
    float tot = red[0] + red[1] + red[2] + red[3];
    float mu = tot * (1.0f / 256.0f);
    float d = v - mu;
    float s2 = d * d;
#pragma unroll
    for (int m = 1; m < 64; m <<= 1) s2 += __shfl_xor(s2, m);
    __syncthreads();
    if ((c & 63) == 0) red[c >> 6] = s2;
    __syncthreads();
    float var = (red[0] + red[1] + red[2] + red[3]) * (1.0f / 256.0f);
    out[idx] = f2bf(d * rsqrtf(var + 1e-5f) * g[c] + bb[c]);
}

// ---------------- fused attention v4: v3 structure, spill-free ----------------
// Per block: (b, h, 256 query rows). Stage K[256][40] + V^T[32][264] once, then 4 x 64-row tiles.
// Per wave per tile: 16 q-rows. S^T = mfma(K_frag, Q_frag) -> lane holds S[q=lrow][k=nf*16+lkg*4+reg].
// PV uses 16x16x32 with the shared k-bijection slot(lkg,e) = 32*nf2 + (e<4 ? lkg*4+e : 16+lkg*4+e-4):
// A-frag = concat(pa[2*nf2], pa[2*nf2+1]) (pure register), B-frag = two ds_read_b64 from Vt.
// v4: exp+bf16-pack fused per fragment pair (acc f32 dies progressively); launch_bounds (256,2)
// so the allocator has a 256-VGPR budget -> no scratch spills (round-3 lesson: (256,4) capped
// VGPRs at 64 and generated 300MB of spill traffic).
#define QROWS 256
__global__ __launch_bounds__(256, 2) void attn_kernel(
    const u16* __restrict__ qbuf, const u16* __restrict__ kvbuf, u16* __restrict__ obuf)
{
    __shared__ __align__(16) u16 Ks[256 * 40];   // 20480 B
    __shared__ __align__(16) u16 Vt[32 * 264];   // 16896 B  Vt[d][k]
    const int qt = blockIdx.x, h = blockIdx.y, b = blockIdx.z;
    const int tid = threadIdx.x;
    const int wid = tid >> 6, lane = tid & 63;
    const int lrow = lane & 15, lkg = lane >> 4;

    // stage K: thread t -> k-row t (4 x 16B)
    {
        const u16* ks = kvbuf + (size_t)(b * 256 + tid) * 512 + h * 32;
        u16* kd = Ks + tid * 40;
#pragma unroll
        for (int c = 0; c < 4; ++c)
            *(int4*)(kd + c * 8) = *(const int4*)(ks + c * 8);
    }
    // stage V^T: thread t reads v-row t, scatters 32 u16 (2-way conflicts only)
    {
        const u16* vs = kvbuf + (size_t)(b * 256 + tid) * 512 + 256 + h * 32;
#pragma unroll
        for (int j = 0; j < 8; ++j) {
            ushort4 vv = *(const ushort4*)(vs + j * 4);
            Vt[(j * 4 + 0) * 264 + tid] = vv.x;
            Vt[(j * 4 + 1) * 264 + tid] = vv.y;
            Vt[(j * 4 + 2) * 264 + tid] = vv.z;
            Vt[(j * 4 + 3) * 264 + tid] = vv.w;
        }
    }
    __syncthreads();

    const float cexp = 0.17677669529663687f * 1.4426950408889634f;
    const int qcol = h * 32 + lkg * 8;

    for (int it = 0; it < QROWS / 64; ++it) {
        const int q0 = qt * QROWS + it * 64 + wid * 16;  // q-row base within batch b
        // Q B-fragment straight from global: contiguous 16B per lane
        bf16x8 qf = *(const bf16x8*)(qbuf + (size_t)(b * 4096 + q0 + lrow) * 256 + qcol);

        f32x4 acc[16];
#pragma unroll
        for (int nf = 0; nf < 16; ++nf) acc[nf] = (f32x4){0.f, 0.f, 0.f, 0.f};
#pragma unroll
        for (int nf = 0; nf < 16; ++nf) {
            bf16x8 kf = *(const bf16x8*)(Ks + (nf * 16 + lrow) * 40 + lkg * 8);
            acc[nf] = __builtin_amdgcn_mfma_f32_16x16x32_bf16(kf, qf, acc[nf], 0, 0, 0);
        }

        // row max over k: 64 values in-lane (q = q0+lrow), then across the 4 lkg groups
        float m0 = -1e30f, m1 = -1e30f, m2 = -1e30f, m3 = -1e30f;
#pragma unroll
        for (int nf = 0; nf < 16; ++nf) {
            m0 = fmaxf(m0, acc[nf][0]); m1 = fmaxf(m1, acc[nf][1]);
            m2 = fmaxf(m2, acc[nf][2]); m3 = fmaxf(m3, acc[nf][3]);
        }
        float m = fmaxf(fmaxf(m0, m1), fmaxf(m2, m3));
        m = fmaxf(m, __shfl_xor(m, 16));
        m = fmaxf(m, __shfl_xor(m, 32));

        // fused exp + bf16 pack: acc f32 dies as pa8 fills (keeps peak VGPR liveness low)
        float s = 0.f;
        bf16x8 pa8[8];
#pragma unroll
        for (int nf2 = 0; nf2 < 8; ++nf2) {
            bf16x8 pv;
#pragma unroll
            for (int half = 0; half < 2; ++half) {
#pragma unroll
                for (int r = 0; r < 4; ++r) {
                    float p = exp2f((acc[2 * nf2 + half][r] - m) * cexp);
                    s += p;
                    pv[half * 4 + r] = (__bf16)p;
                }
            }
            pa8[nf2] = pv;
        }
        s += __shfl_xor(s, 16);
        s += __shfl_xor(s, 32);
        const float inv = 1.0f / s;

        // O = P @ V via 16x16x32 with matching B-side bijection (two b64 reads per frag)
        f32x4 o0 = (f32x4){0.f, 0.f, 0.f, 0.f};
        f32x4 o1 = (f32x4){0.f, 0.f, 0.f, 0.f};
#pragma unroll
        for (int nf2 = 0; nf2 < 8; ++nf2) {
            bf16x4 lo0 = *(const bf16x4*)(Vt + lrow * 264 + nf2 * 32 + lkg * 4);
            bf16x4 hi0 = *(const bf16x4*)(Vt + lrow * 264 + nf2 * 32 + 16 + lkg * 4);
            bf16x4 lo1 = *(const bf16x4*)(Vt + (16 + lrow) * 264 + nf2 * 32 + lkg * 4);
            bf16x4 hi1 = *(const bf16x4*)(Vt + (16 + lrow) * 264 + nf2 * 32 + 16 + lkg * 4);
            bf16x8 v0 = __builtin_shufflevector(lo0, hi0, 0, 1, 2, 3, 4, 5, 6, 7);
            bf16x8 v1 = __builtin_shufflevector(lo1, hi1, 0, 1, 2, 3, 4, 5, 6, 7);
            o0 = __builtin_amdgcn_mfma_f32_16x16x32_bf16(pa8[nf2], v0, o0, 0, 0, 0);
            o1 = __builtin_amdgcn_mfma_f32_16x16x32_bf16(pa8[nf2], v1, o1, 0, 0, 0);
        }

        // deferred 1/sum: gather inv for q = q0 + lkg*4 + r from lanes 0..15
        float invq[4];
#pragma unroll
        for (int r = 0; r < 4; ++r) invq[r] = __shfl(inv, lkg * 4 + r);

        const size_t obase = (size_t)(b * 4096 + q0);
#pragma unroll
        for (int r = 0; r < 4; ++r) {
            u16* op = obuf + (obase + lkg * 4 + r) * 256 + h * 32 + lrow;
            op[0]  = f2bf(o0[r] * invq[r]);
            op[16] = f2bf(o1[r] * invq[r]);
        }
    }
}

extern "C" void kernel_launch(void* const* d_in, const int* in_sizes, int n_in,
                              void* d_out, int out_size, void* d_ws, size_t ws_size,
                              hipStream_t stream)
{
    (void)in_sizes; (void)n_in; (void)out_size; (void)ws_size;
    const float* x   = (const float*)d_in[0];
    const float* qw  = (const float*)d_in[3];
    const float* qb  = (const float*)d_in[4];
    const float* kvw = (const float*)d_in[5];
    const float* kvb = (const float*)d_in[6];
    const float* srw = (const float*)d_in[7];
    const float* srb = (const float*)d_in[8];
    const float* lng = (const float*)d_in[9];
    const float* lnb = (const float*)d_in[10];
    const float* pw  = (const float*)d_in[11];
    const float* pb  = (const float*)d_in[12];

    char* ws = (char*)d_ws;
    u16*   xb      = (u16*)(ws + 0);          // 16.78 MB  x as bf16 [32768][256]
    u16*   patches = (u16*)(ws + 16777216);   // 16.78 MB  im2col [2048][4096]; later reused as attn_out
    float* part    = (float*)(ws + 33554432); //  8.39 MB  conv split-K partials [4][2048][256]
    u16*   wsr     = (u16*)(ws + 41943040);   //  2.10 MB
    u16*   wqb     = (u16*)(ws + 44040192);
    u16*   wkvb    = (u16*)(ws + 44171264);
    u16*   wpb     = (u16*)(ws + 44433408);
    u16*   xsr     = (u16*)(ws + 44564480);   //  1.05 MB  LN output bf16 [2048][256]
    u16*   kvo     = (u16*)(ws + 45613056);   //  2.10 MB  kv bf16 [2048][512]
    u16*   qbuf    = (u16*)d_out;             // q bf16 [32768][256] in d_out scratch (overwritten by proj)

    prep_w<<<1024, 256, 0, stream>>>(qw, kvw, pw, srw, wqb, wkvb, wpb, wsr);
    prep_x<<<8192, 256, 0, stream>>>(x, xb, patches);
    // conv as GEMM, split-K x4 -> f32 partials
    gemm128<2><<<dim3(16, 2, 4), 256, 0, stream>>>(patches, wsr, nullptr, part, 2048, 256, 4096, 1024);
    ln_kernel<<<2048, 256, 0, stream>>>(part, srb, lng, lnb, xsr);
    gemm128<1><<<dim3(16, 4, 1), 256, 0, stream>>>(xsr, wkvb, kvb, kvo, 2048, 512, 256, 256);
    gemm128<1><<<dim3(256, 2, 1), 256, 0, stream>>>(xb, wqb, qb, qbuf, 32768, 256, 256, 256);
    attn_kernel<<<dim3(16, 8, 8), 256, 0, stream>>>(qbuf, kvo, patches);
    gemm128<0><<<dim3(256, 2, 1), 256, 0, stream>>>(patches, wpb, pb, d_out, 32768, 256, 256, 256);
}